// Round 4
// baseline (347.447 us; speedup 1.0000x reference)
//
#include <hip/hip_runtime.h>
#include <math.h>

// NSA attention (round 16: fix round-15 overflow. Round 15's fused
// scorecand_kernel was correct in structure but CAP=192 overflowed: the
// min-of-16-tracked (top-2 per thread) threshold has tail ~36/n vs exact
// T16's 16/n -> E[cand] ~ 145/row, sigma ~ 20; CAP=192 = +2sigma -> ~2% of
// rows dropped true winners (absmax 0.25). CAP=512 = +15sigma (134 MB ws).
// Superset proof unchanged: M(t) = min of 16 tracked seen-values <=
// T16(seen<=t) <= T16(full row), and thresholds only grow, so emitting
// s >= M(t) at strip t never loses a final top-16 member.
// Candidates are u64 ordinals ((f2o(s)^0x80000000)<<11 | 2047-key) = exact
// jax (value desc, key asc) order; seltopk2 warp-bitonic-merges <=8 batches
// of 64 (1 u64/lane, no arrays -> no scratch) + softmax/V epilogue.
// Score matrix never hits HBM: 536 MB round-trip -> ~76 MB.
// B=2 L=2048 C=256 H=8 HD=32 BS=16 SK=16 win=+-32.

#define Bc 2
#define Lc 2048
#define Cc 256
#define Hc 8
#define HDc 32
#define BHc 16          // B*H
#define NBc 128         // L/BS
#define ROWSc 4096      // B*L
#define TROWSc 32768    // B*H*L
#define CAPc 512        // candidate slots per row (mean ~145, +15 sigma)
#define SCALEc 0.17677669529663687f

typedef unsigned long long u64;

// ---------- helpers ----------

__device__ __forceinline__ float dot32q(const float* qr, const float* kr) {
  const float4* k4 = (const float4*)kr;
  float p0 = 0.f, p1 = 0.f, p2 = 0.f, p3 = 0.f;
#pragma unroll
  for (int j = 0; j < 8; j += 4) {
    float4 a = k4[j], b = k4[j + 1], c = k4[j + 2], e = k4[j + 3];
    p0 += a.x * qr[4 * j + 0] + a.y * qr[4 * j + 1] + a.z * qr[4 * j + 2] + a.w * qr[4 * j + 3];
    p1 += b.x * qr[4 * j + 4] + b.y * qr[4 * j + 5] + b.z * qr[4 * j + 6] + b.w * qr[4 * j + 7];
    p2 += c.x * qr[4 * j + 8] + c.y * qr[4 * j + 9] + c.z * qr[4 * j + 10] + c.w * qr[4 * j + 11];
    p3 += e.x * qr[4 * j + 12] + e.y * qr[4 * j + 13] + e.z * qr[4 * j + 14] + e.w * qr[4 * j + 15];
  }
  return (p0 + p1) + (p2 + p3);
}

// order-preserving float<->int maps
__device__ __forceinline__ int f2o(float x) {
  const int i = __float_as_int(x);
  return i >= 0 ? i : (i ^ 0x7fffffff);
}
__device__ __forceinline__ float o2f(int i) {
  return __int_as_float(i >= 0 ? i : (i ^ 0x7fffffff));
}

__device__ __forceinline__ u64 shflx64(u64 v, int mask) {
  const int lo = __shfl_xor((int)(unsigned)(v & 0xffffffffull), mask);
  const int hi = __shfl_xor((int)(unsigned)(v >> 32), mask);
  return ((u64)(unsigned)hi << 32) | (u64)(unsigned)lo;
}
__device__ __forceinline__ u64 shfl64(u64 v, int src) {
  const int lo = __shfl((int)(unsigned)(v & 0xffffffffull), src);
  const int hi = __shfl((int)(unsigned)(v >> 32), src);
  return ((u64)(unsigned)hi << 32) | (u64)(unsigned)lo;
}

// full warp (64-lane) bitonic sort, descending by u64; state = 1 reg/lane
__device__ __forceinline__ void warp_sort64(u64& t, int lane) {
#pragma unroll
  for (int kk = 2; kk <= 64; kk <<= 1) {
#pragma unroll
    for (int j = kk >> 1; j >= 1; j >>= 1) {
      const u64 o = shflx64(t, j);
      const bool keep_min = (((lane & kk) != 0) == ((lane & j) == 0));
      const bool g = t > o;
      t = (g == keep_min) ? o : t;
    }
  }
}

// ---------- projections ----------
// X(4096,256) @ W(256,256) + bias. headlayout=1: store [b*H+h][l][d]; else [row][c].
__global__ __launch_bounds__(256) void proj_kernel(const float* __restrict__ X,
                                                   const float* __restrict__ W,
                                                   const float* __restrict__ bias,
                                                   float* __restrict__ outp, int headlayout) {
  __shared__ float xs[8 * Cc];
  const int tid = threadIdx.x;
  const int row0 = blockIdx.x * 8;
  {
    const float4* xin = (const float4*)(X + (size_t)row0 * Cc);
    float4* xsv = (float4*)xs;
    xsv[tid] = xin[tid];
    xsv[tid + 256] = xin[tid + 256];
  }
  __syncthreads();
  const int c0 = (tid & 63) * 4;  // 4 consecutive cols
  const int rh = tid >> 6;        // wave id; 2 rows per wave
  float acc[2][4];
#pragma unroll
  for (int r = 0; r < 2; ++r)
#pragma unroll
    for (int c = 0; c < 4; ++c) acc[r][c] = 0.f;

#pragma unroll 4
  for (int d4 = 0; d4 < 64; ++d4) {
    const int d = d4 * 4;
    const float4 w0 = *(const float4*)(W + (size_t)(d + 0) * Cc + c0);
    const float4 w1 = *(const float4*)(W + (size_t)(d + 1) * Cc + c0);
    const float4 w2 = *(const float4*)(W + (size_t)(d + 2) * Cc + c0);
    const float4 w3 = *(const float4*)(W + (size_t)(d + 3) * Cc + c0);
#pragma unroll
    for (int r = 0; r < 2; ++r) {
      const float4 xv = *(const float4*)(xs + (rh * 2 + r) * Cc + d);
      acc[r][0] += xv.x * w0.x + xv.y * w1.x + xv.z * w2.x + xv.w * w3.x;
      acc[r][1] += xv.x * w0.y + xv.y * w1.y + xv.z * w2.y + xv.w * w3.y;
      acc[r][2] += xv.x * w0.z + xv.y * w1.z + xv.z * w2.z + xv.w * w3.z;
      acc[r][3] += xv.x * w0.w + xv.y * w1.w + xv.z * w2.w + xv.w * w3.w;
    }
  }
  const float4 bv = *(const float4*)(bias + c0);
#pragma unroll
  for (int r = 0; r < 2; ++r) {
    const int grow = row0 + rh * 2 + r;
    const float4 o = make_float4(acc[r][0] + bv.x, acc[r][1] + bv.y,
                                 acc[r][2] + bv.z, acc[r][3] + bv.w);
    if (headlayout) {
      const int b = grow >> 11, l = grow & 2047;
      const int h = c0 >> 5, dd = c0 & 31;
      *(float4*)(outp + (((size_t)(b * Hc + h) * Lc + l) * HDc + dd)) = o;
    } else {
      *(float4*)(outp + (size_t)grow * Cc + c0) = o;
    }
  }
}

// gate = sigmoid(query @ Wg + bg), one thread per row
__global__ __launch_bounds__(256) void gate_kernel(const float* __restrict__ query,
                                                   const float* __restrict__ Wg,
                                                   const float* __restrict__ bg,
                                                   float* __restrict__ gatep) {
  const int row = blockIdx.x * 256 + threadIdx.x;
  const float4* x4 = (const float4*)(query + (size_t)row * Cc);
  float a0 = bg[0], a1 = bg[1], a2 = bg[2];
#pragma unroll 8
  for (int d4 = 0; d4 < 64; ++d4) {
    const float4 xv = x4[d4];
    const float* wr = Wg + d4 * 12;
    a0 += xv.x * wr[0] + xv.y * wr[3] + xv.z * wr[6] + xv.w * wr[9];
    a1 += xv.x * wr[1] + xv.y * wr[4] + xv.z * wr[7] + xv.w * wr[10];
    a2 += xv.x * wr[2] + xv.y * wr[5] + xv.z * wr[8] + xv.w * wr[11];
  }
  float* g = gatep + (size_t)row * 3;
  g[0] = 1.f / (1.f + __expf(-a0));
  g[1] = 1.f / (1.f + __expf(-a1));
  g[2] = 1.f / (1.f + __expf(-a2));
}

// ---------- compressed K/V ----------
__global__ __launch_bounds__(256) void cmpkv_kernel(const float* __restrict__ kh,
                                                    const float* __restrict__ vh,
                                                    const float* __restrict__ WKc,
                                                    const float* __restrict__ WVc,
                                                    const float* __restrict__ Wpe,
                                                    float* __restrict__ Kcp,
                                                    float* __restrict__ Vcp) {
  const int idx = blockIdx.x * 256 + threadIdx.x;  // 65536 = bh*128*32
  const int d = idx & 31, n = (idx >> 5) & 127, bh = idx >> 12;
  float pk = 0.f, pv = 0.f;
#pragma unroll
  for (int s = 0; s < 16; ++s) {
    const float pe = Wpe[s * Cc + d];
    pk += pe * WKc[s];
    pv += pe * WVc[s];
  }
  const float* kp = kh + ((size_t)bh * Lc + n * 16) * HDc + d;
  const float* vp = vh + ((size_t)bh * Lc + n * 16) * HDc + d;
  float ak = pk, av = pv;
#pragma unroll
  for (int s = 0; s < 16; ++s) {
    ak += kp[s * HDc] * WKc[s];
    av += vp[s * HDc] * WVc[s];
  }
  Kcp[idx] = ak;
  Vcp[idx] = av;
}

// ---------- compressed attention ----------
__global__ __launch_bounds__(512) void cmp_attn_kernel(const float* __restrict__ qh,
                                                       const float* __restrict__ Kcp,
                                                       const float* __restrict__ Vcp,
                                                       float* __restrict__ ocmp) {
  __shared__ float sc[128][65];
  __shared__ float pm[8][64];
  const int tid = threadIdx.x, lane = tid & 63;
  const int w = __builtin_amdgcn_readfirstlane(tid >> 6);
  const int bh = blockIdx.y;
  const int lrow = blockIdx.x * 64 + lane;
  const float* q = qh + ((size_t)bh * Lc + lrow) * HDc;
  float qr[HDc];
#pragma unroll
  for (int d = 0; d < HDc; ++d) qr[d] = q[d] * SCALEc;
  const float* kcb = Kcp + (size_t)bh * NBc * HDc;
  float pmax = -1e30f;
#pragma unroll
  for (int i = 0; i < 16; ++i) {
    const int key = w * 16 + i;  // uniform
    const float s = dot32q(qr, kcb + (size_t)key * HDc);
    sc[key][lane] = s;
    pmax = fmaxf(pmax, s);
  }
  pm[w][lane] = pmax;
  __syncthreads();

  const int row = tid >> 3;        // 0..63
  const int dg = (tid & 7) * 4;    // dim-group base
  float m = pm[0][row];
#pragma unroll
  for (int i = 1; i < 8; ++i) m = fmaxf(m, pm[i][row]);
  const float* vcb = Vcp + (size_t)bh * NBc * HDc + dg;
  float o0 = 0.f, o1 = 0.f, o2 = 0.f, o3 = 0.f, z = 0.f;
#pragma unroll 4
  for (int key = 0; key < 128; ++key) {
    const float wgt = __expf(sc[key][row] - m);
    z += wgt;
    const float4 v = *(const float4*)(vcb + key * HDc);
    o0 += wgt * v.x; o1 += wgt * v.y; o2 += wgt * v.z; o3 += wgt * v.w;
  }
  const float iz = 1.f / z;
  *(float4*)(ocmp + ((size_t)bh * Lc + blockIdx.x * 64 + row) * HDc + dg) =
      make_float4(o0 * iz, o1 * iz, o2 * iz, o3 * iz);
}

// ---------- fused selection scores + candidate emission ----------
// Grid (32 rowblocks, 16 heads), block 512 = 8 waves / 64 rows. 32 strips of
// 64 keys. Compute phase (lane=row, wave-uniform s_load K) -> LDS transpose.
// Candidate phase: thread (srow=tid>>3, skg=(tid&7)*8) reads its 8 strip
// scores, updates a running top-2 (mx,m2); M = 8-thread subgroup-min of m2
// (16 tracked seen-values => M <= T16(seen) <= T16(row) always). Every score
// >= M is appended to the row's candidate list (LDS atomic counter, u64
// ordinal packing). E[count] ~ 145, CAP 512. No score reaches HBM.
__global__ __launch_bounds__(512) void scorecand_kernel(const float* __restrict__ qh,
                                                        const float* __restrict__ kh,
                                                        u64* __restrict__ cand,
                                                        unsigned* __restrict__ cntg) {
  __shared__ float sc[64][65];
  __shared__ unsigned cnt_l[64];
  const int tid = threadIdx.x, lane = tid & 63;
  const int w = __builtin_amdgcn_readfirstlane(tid >> 6);  // wave id (SGPR)
  const int bh = blockIdx.y;
  const int lrow = blockIdx.x * 64 + lane;  // compute-phase row
  const float* q = qh + ((size_t)bh * Lc + lrow) * HDc;
  float qr[HDc];
#pragma unroll
  for (int d = 0; d < HDc; ++d) qr[d] = q[d] * SCALEc;
  const float* kb = kh + (size_t)bh * Lc * HDc;
  const int srow = tid >> 3;        // candidate-phase row 0..63
  const int skg = (tid & 7) * 8;    // key-group base within strip
  const int growbase = bh * Lc + blockIdx.x * 64;
  u64* crow = cand + (size_t)(growbase + srow) * CAPc;
  if (tid < 64) cnt_l[tid] = 0u;
  float mx = -INFINITY, m2 = -INFINITY;

  for (int strip = 0; strip < 32; ++strip) {
    const int k0 = strip * 64 + w * 8;  // uniform (SGPR) expression
    float s[8];
#pragma unroll
    for (int j = 0; j < 8; ++j) s[j] = dot32q(qr, kb + (size_t)(k0 + j) * HDc);
    __syncthreads();  // prior candidate phase finished reading sc (iter0: cnt_l init)
#pragma unroll
    for (int j = 0; j < 8; ++j) sc[w * 8 + j][lane] = s[j];
    __syncthreads();
    // candidate phase: read my row's 8 scores of this strip
    float v[8];
#pragma unroll
    for (int j = 0; j < 8; ++j) v[j] = sc[skg + j][srow];
    // running top-2 update
#pragma unroll
    for (int j = 0; j < 8; ++j) {
      m2 = fmaxf(m2, fminf(mx, v[j]));
      mx = fmaxf(mx, v[j]);
    }
    // threshold: min of the row's 8 threads' m2 (consecutive 8-lane group)
    float M = m2;
    M = fminf(M, __shfl_xor(M, 1));
    M = fminf(M, __shfl_xor(M, 2));
    M = fminf(M, __shfl_xor(M, 4));
    // emit candidates >= M
    unsigned hits = 0u;
#pragma unroll
    for (int j = 0; j < 8; ++j) hits |= (v[j] >= M ? 1u : 0u) << j;
    const int nh = __popc(hits);
    if (nh) {
      unsigned pos = atomicAdd(&cnt_l[srow], (unsigned)nh);
#pragma unroll
      for (int j = 0; j < 8; ++j) {
        if (hits & (1u << j)) {
          if (pos < CAPc) {
            const int key = strip * 64 + skg + j;
            const unsigned uo = (unsigned)f2o(v[j]) ^ 0x80000000u;
            crow[pos] = ((u64)uo << 11) | (u64)(2047 - key);
          }
          ++pos;
        }
      }
    }
  }
  __syncthreads();
  if (tid < 64) {
    const unsigned c = cnt_l[tid];
    cntg[growbase + tid] = c < CAPc ? c : (unsigned)CAPc;
  }
}

// ---------- candidate merge -> top-16 + softmax + V ----------
// One wave per row. cnt candidates (16 <= cnt <= 512, superset of top-16).
// Sort first 64 slots (warp bitonic on the u64 ordinal: value desc, key asc
// exactly); for each further batch: sort, reverse-max, 6-stage descending
// cleanup -> running top-64. Lanes 0..15 then hold the exact sorted top-16.
__global__ __launch_bounds__(256) void seltopk2_kernel(const u64* __restrict__ cand,
                                                       const unsigned* __restrict__ cntg,
                                                       const float* __restrict__ vh,
                                                       float* __restrict__ oslc) {
  __shared__ float lsv[4][16];
  __shared__ unsigned lsk[4][16];
  const int wave = threadIdx.x >> 6, lane = threadIdx.x & 63;
  const int r = blockIdx.x * 4 + wave;  // 1 row per wave
  const int bh = r >> 11;
  const int l = r & 2047;
  const int cnt = (int)__builtin_amdgcn_readfirstlane(cntg[r]);
  const u64* crow = cand + (size_t)r * CAPc;

  u64 t = (lane < cnt) ? crow[lane] : 0ull;
  warp_sort64(t, lane);
  for (int b = 64; b < cnt; b += 64) {  // wave-uniform loop (<= 8 iters, ~3 typ.)
    u64 u = (b + lane < cnt) ? crow[b + lane] : 0ull;
    warp_sort64(u, lane);
    const u64 rv = shfl64(u, 63 - lane);
    t = t > rv ? t : rv;  // top-64 of 128, bitonic
#pragma unroll
    for (int j = 32; j >= 1; j >>= 1) {  // descending cleanup
      const u64 o = shflx64(t, j);
      const bool keep_min = ((lane & j) != 0);
      const bool g = t > o;
      t = (g == keep_min) ? o : t;
    }
  }

  // broadcast sorted top-16, fused softmax + V gather
  if (lane < 16) {
    lsv[wave][lane] = o2f((int)((unsigned)(t >> 11) ^ 0x80000000u));
    lsk[wave][lane] = 2047u - (unsigned)(t & 0x7ffu);
  }
  __asm__ volatile("s_waitcnt lgkmcnt(0)" ::: "memory");

  const float mtop = lsv[wave][0];
  const int d = lane & 31;
  const float* vb = vh + (size_t)bh * Lc * HDc + d;
  float z = 0.f, oacc = 0.f;
#pragma unroll
  for (int i = 0; i < 16; ++i) {
    const float w_ = __expf(lsv[wave][i] - mtop);
    z += w_;
    oacc += w_ * vb[(size_t)lsk[wave][i] * HDc];
  }
  if (lane < 32) oslc[((size_t)bh * Lc + l) * HDc + d] = oacc / z;
}

// ---------- window attention (±32 band) ----------
__global__ __launch_bounds__(512) void win_attn_kernel(const float* __restrict__ qh,
                                                       const float* __restrict__ kh,
                                                       const float* __restrict__ vh,
                                                       float* __restrict__ owin) {
  __shared__ float sc[128][65];
  __shared__ float pm[8][64];
  const int tid = threadIdx.x, lane = tid & 63;
  const int w = __builtin_amdgcn_readfirstlane(tid >> 6);
  const int bh = blockIdx.y;
  const int l0 = blockIdx.x * 64;
  const int lrow = l0 + lane;
  const float* q = qh + ((size_t)bh * Lc + lrow) * HDc;
  float qr[HDc];
#pragma unroll
  for (int d = 0; d < HDc; ++d) qr[d] = q[d] * SCALEc;
  const float* kb = kh + (size_t)bh * Lc * HDc;
  float pmax = -1e30f;
#pragma unroll
  for (int i = 0; i < 16; ++i) {
    const int j = w * 16 + i;            // 0..127 (uniform)
    const int key = l0 - 32 + j;         // absolute key (uniform)
    const int keyc = min(max(key, 0), Lc - 1);  // uniform clamp for the load
    float s = dot32q(qr, kb + (size_t)keyc * HDc);
    const int delta = key - lrow;        // lane-varying
    const bool ok = (key >= 0) && (key < Lc) && (delta >= -32) && (delta <= 32);
    s = ok ? s : -1e30f;
    sc[j][lane] = s;
    pmax = fmaxf(pmax, s);
  }
  pm[w][lane] = pmax;
  __syncthreads();

  const int row = tid >> 3;
  const int dg = (tid & 7) * 4;
  float m = pm[0][row];
#pragma unroll
  for (int i = 1; i < 8; ++i) m = fmaxf(m, pm[i][row]);
  const float* vb = vh + (size_t)bh * Lc * HDc + dg;
  float o0 = 0.f, o1 = 0.f, o2 = 0.f, o3 = 0.f, z = 0.f;
#pragma unroll 4
  for (int j = 0; j < 128; ++j) {
    const float wgt = __expf(sc[j][row] - m);  // 0 for masked entries
    z += wgt;
    const int keyc = min(max(l0 - 32 + j, 0), Lc - 1);
    const float4 v = *(const float4*)(vb + (size_t)keyc * HDc);
    o0 += wgt * v.x; o1 += wgt * v.y; o2 += wgt * v.z; o3 += wgt * v.w;
  }
  const float iz = 1.f / z;
  *(float4*)(owin + ((size_t)bh * Lc + l0 + row) * HDc + dg) =
      make_float4(o0 * iz, o1 * iz, o2 * iz, o3 * iz);
}

// ---------- gated combine into merged (B,L,C) ----------
__global__ __launch_bounds__(256) void combine_kernel(const float* __restrict__ ocmp,
                                                      const float* __restrict__ oslc,
                                                      const float* __restrict__ owin,
                                                      const float* __restrict__ gatep,
                                                      float* __restrict__ xm) {
  const int idx = blockIdx.x * 256 + threadIdx.x;  // 4096 rows * 64 float4-groups
  const int c4 = idx & 63, grow = idx >> 6;
  const int b = grow >> 11, l = grow & 2047;
  const int h = c4 >> 3, d4 = (c4 & 7) * 4;
  const size_t hoff = (((size_t)(b * Hc + h) * Lc + l)) * HDc + d4;
  const float g0 = gatep[(size_t)grow * 3 + 0];
  const float g1 = gatep[(size_t)grow * 3 + 1];
  const float g2 = gatep[(size_t)grow * 3 + 2];
  const float4 a = *(const float4*)(ocmp + hoff);
  const float4 s = *(const float4*)(oslc + hoff);
  const float4 w = *(const float4*)(owin + hoff);
  float4 r;
  r.x = g0 * a.x + g1 * s.x + g2 * w.x;
  r.y = g0 * a.y + g1 * s.y + g2 * w.y;
  r.z = g0 * a.z + g1 * s.z + g2 * w.z;
  r.w = g0 * a.w + g1 * s.w + g2 * w.w;
  *(float4*)(xm + (size_t)grow * Cc + c4 * 4) = r;
}

// ---------- launch ----------
extern "C" void kernel_launch(void* const* d_in, const int* in_sizes, int n_in,
                              void* d_out, int out_size, void* d_ws, size_t ws_size,
                              hipStream_t stream) {
  (void)in_sizes; (void)n_in; (void)out_size; (void)ws_size;
  const float* query = (const float*)d_in[0];
  const float* key   = (const float*)d_in[1];
  const float* value = (const float*)d_in[2];
  const float* Wq = (const float*)d_in[3];
  const float* bq = (const float*)d_in[4];
  const float* Wk = (const float*)d_in[5];
  const float* bk = (const float*)d_in[6];
  const float* Wv = (const float*)d_in[7];
  const float* bv = (const float*)d_in[8];
  const float* Wo = (const float*)d_in[9];
  const float* bo = (const float*)d_in[10];
  const float* WKc = (const float*)d_in[11];
  const float* WVc = (const float*)d_in[12];
  const float* Wpe = (const float*)d_in[13];
  const float* Wg = (const float*)d_in[14];
  const float* bg = (const float*)d_in[15];

  size_t off = 0;
  auto alloc = [&](size_t bytes) -> void* {
    void* p = (char*)d_ws + off;
    off += (bytes + 255) & ~(size_t)255;
    return p;
  };
  float* qh    = (float*)alloc((size_t)TROWSc * HDc * 4);
  float* kh    = (float*)alloc((size_t)TROWSc * HDc * 4);
  float* vh    = (float*)alloc((size_t)TROWSc * HDc * 4);
  float* gatep = (float*)alloc((size_t)ROWSc * 3 * 4);
  float* Kcp   = (float*)alloc((size_t)BHc * NBc * HDc * 4);
  float* Vcp   = (float*)alloc((size_t)BHc * NBc * HDc * 4);
  float* ocmp  = (float*)alloc((size_t)TROWSc * HDc * 4);
  float* oslc  = (float*)alloc((size_t)TROWSc * HDc * 4);
  float* owin  = (float*)alloc((size_t)TROWSc * HDc * 4);
  float* xm    = (float*)alloc((size_t)ROWSc * Cc * 4);
  u64*      cand = (u64*)alloc((size_t)TROWSc * CAPc * 8);
  unsigned* cntg = (unsigned*)alloc((size_t)TROWSc * 4);

  proj_kernel<<<dim3(512), 256, 0, stream>>>(query, Wq, bq, qh, 1);
  proj_kernel<<<dim3(512), 256, 0, stream>>>(key, Wk, bk, kh, 1);
  proj_kernel<<<dim3(512), 256, 0, stream>>>(value, Wv, bv, vh, 1);
  gate_kernel<<<dim3(16), 256, 0, stream>>>(query, Wg, bg, gatep);
  cmpkv_kernel<<<dim3(256), 256, 0, stream>>>(kh, vh, WKc, WVc, Wpe, Kcp, Vcp);
  cmp_attn_kernel<<<dim3(32, 16), 512, 0, stream>>>(qh, Kcp, Vcp, ocmp);
  scorecand_kernel<<<dim3(32, 16), 512, 0, stream>>>(qh, kh, cand, cntg);
  seltopk2_kernel<<<dim3(TROWSc / 4), 256, 0, stream>>>(cand, cntg, vh, oslc);
  win_attn_kernel<<<dim3(32, 16), 512, 0, stream>>>(qh, kh, vh, owin);
  combine_kernel<<<dim3(1024), 256, 0, stream>>>(ocmp, oslc, owin, gatep, xm);
  proj_kernel<<<dim3(512), 256, 0, stream>>>(xm, Wo, bo, (float*)d_out, 0);
}